// Round 6
// baseline (212.984 us; speedup 1.0000x reference)
//
#include <hip/hip_runtime.h>
#include <hip/hip_bf16.h>

#define NTOT (4*256*256)      // 262144 feature rows
#define DIM 384
#define KCL 256               // clusters
#define BM 64                 // rows per block tile
#define BK 32                 // k-step
#define TBS 256               // threads per block
#define GRID_MAIN (NTOT/BM)   // 4096 blocks
#define NT (DIM/BK)           // 12 K-steps
#define EPS 1e-12f

// LDS map (bytes): A double-buffer 2 x (AH 4K | AL 4K) = 16 KiB, then
// B wave-private regions 4 x (hi 4K | lo 4K) = 32 KiB.  Total 48 KiB -> 3 blocks/CU.
#define ABUF(p)   ((p) * 8192)
#define AHI 0
#define ALO 4096
#define BPRIV     16384

typedef __attribute__((ext_vector_type(8))) _Float16 f16x8;
typedef __attribute__((ext_vector_type(4))) float f32x4;

__device__ __forceinline__ void async_copy16(const void* gptr, void* lptr) {
    __builtin_amdgcn_global_load_lds(
        (const __attribute__((address_space(1))) unsigned int*)gptr,
        (__attribute__((address_space(3))) unsigned int*)lptr, 16, 0, 0);
}

// ---------------------------------------------------------------------------
// Pre-pass: L2-normalize clusters; emit fp16 hi/lo in STAGE-ORDER layout:
// element (cluster j, dim d) -> fp16 index
//   ((d>>5)*1024 + (j>>4)*64 + ((d>>3)&3)*16 + (j&15))*8 + (d&7)
// so a wave's 8 stage/frag accesses per K-step are contiguous 1 KiB each.
// ---------------------------------------------------------------------------
__global__ void prep_clusters(const float* __restrict__ cc,
                              _Float16* __restrict__ bh, _Float16* __restrict__ bl) {
    int j = blockIdx.x, l = threadIdx.x;   // 256 blocks x 64 lanes
    float v[6]; float ssq = 0.f;
#pragma unroll
    for (int i = 0; i < 6; ++i) { v[i] = cc[j*DIM + l + 64*i]; ssq = fmaf(v[i], v[i], ssq); }
#pragma unroll
    for (int off = 32; off >= 1; off >>= 1) ssq += __shfl_xor(ssq, off);
    float inv = 1.f / fmaxf(sqrtf(ssq), EPS);
#pragma unroll
    for (int i = 0; i < 6; ++i) {
        int d = l + 64 * i;
        float x = v[i] * inv;
        _Float16 h  = (_Float16)x;
        _Float16 lo = (_Float16)(x - (float)h);
        size_t idx = (size_t)(((d >> 5) * 1024 + (j >> 4) * 64 + ((d >> 3) & 3) * 16 + (j & 15)) * 8
                              + (d & 7));
        bh[idx] = h;
        bl[idx] = lo;
    }
}

// ---------------------------------------------------------------------------
// Main: split-fp16 16x16x32 MFMA GEMM.
//  - A: shared 16 KiB LDS double-buffer, 1 lgkm-barrier per step, depth-2
//    f32 register prefetch (HBM latency covered by a full step).
//  - B: wave-private single-buffered LDS (8 KiB/wave), synced by per-wave
//    waitcnt only; gl_lds for t+1 issued pre-barrier, flies under the MFMAs.
// ---------------------------------------------------------------------------
__global__ __launch_bounds__(TBS, 3)
void kmeans_main(const float* __restrict__ A,    // features [NTOT][384] f32
                 const float* __restrict__ W,    // weight   [NTOT]
                 const _Float16* __restrict__ Bh,// stage-order hi
                 const _Float16* __restrict__ Bl,// stage-order lo
                 const int*   __restrict__ PA,   // [256]
                 float* __restrict__ out,        // [2*NTOT+1]
                 float* __restrict__ partial)    // [GRID_MAIN]
{
    __shared__ unsigned char smem[49152];

    const int tid  = threadIdx.x;
    const int wv   = tid >> 6;        // wave 0..3 -> cols [64*wv, 64*wv+64)
    const int lane = tid & 63;
    const int g    = lane >> 4;       // k-group 0..3
    const int l15  = lane & 15;
    const int sw   = (l15 >> 1) & 3;  // A read-side swizzle term (R3, 0-conflict)
    const int row0 = blockIdx.x * BM;
    const int arow = tid >> 2, achk = tid & 3;        // A loader mapping
    const int awb  = (((arow << 2) + (achk ^ ((arow >> 1) & 3))) << 4);
    const int fa   = l15 * 64 + ((g ^ sw) << 4);      // A frag base (+m*1024)

    const int bpb  = BPRIV + wv * 8192 + lane * 16;   // B wave-private lane base
    const unsigned char* bhsrc = (const unsigned char*)Bh + (size_t)(4 * wv) * 1024 + lane * 16;
    const unsigned char* blsrc = (const unsigned char*)Bl + (size_t)(4 * wv) * 1024 + lane * 16;

    const float* aptr = A + (size_t)(row0 + arow) * DIM + achk * 8;

    f32x4 acc[4][4];
#pragma unroll
    for (int m = 0; m < 4; ++m)
#pragma unroll
        for (int n = 0; n < 4; ++n) acc[m][n] = (f32x4){0.f, 0.f, 0.f, 0.f};
    float ssq = 0.f;

    auto stageB = [&](int t) {   // 8 x gl_lds into this wave's private region
        const unsigned char* sh = bhsrc + (size_t)t * 16384;
        const unsigned char* sl = blsrc + (size_t)t * 16384;
#pragma unroll
        for (int n = 0; n < 4; ++n) {
            async_copy16(sh + n * 1024, smem + bpb + n * 1024);
            async_copy16(sl + n * 1024, smem + bpb + 4096 + n * 1024);
        }
    };
    auto writeA = [&](const float4& x0, const float4& x1, int q) {
        float av[8] = {x0.x, x0.y, x0.z, x0.w, x1.x, x1.y, x1.z, x1.w};
        f16x8 h8, l8;
#pragma unroll
        for (int w = 0; w < 8; ++w) {
            _Float16 hh = (_Float16)av[w];
            h8[w] = hh;
            l8[w] = (_Float16)(av[w] - (float)hh);
            ssq = fmaf(av[w], av[w], ssq);
        }
        *(f16x8*)(smem + ABUF(q) + AHI + awb) = h8;
        *(f16x8*)(smem + ABUF(q) + ALO + awb) = l8;
    };

    f16x8 bhf[4], blf[4];
    auto readB = [&]() {
#pragma unroll
        for (int n = 0; n < 4; ++n) {
            bhf[n] = *(const f16x8*)(smem + bpb + n * 1024);
            blf[n] = *(const f16x8*)(smem + bpb + 4096 + n * 1024);
        }
    };
    auto mfmaBlock = [&](int p) {
        f16x8 ahf[4], alf[4];
#pragma unroll
        for (int m = 0; m < 4; ++m) {
            ahf[m] = *(const f16x8*)(smem + ABUF(p) + AHI + fa + m * 1024);
            alf[m] = *(const f16x8*)(smem + ABUF(p) + ALO + fa + m * 1024);
        }
        asm volatile("s_barrier" ::: "memory");   // read-issue fence: Abuf[p] safe
        __builtin_amdgcn_s_setprio(1);
#pragma unroll
        for (int m = 0; m < 4; ++m)
#pragma unroll
            for (int n = 0; n < 4; ++n)
                acc[m][n] = __builtin_amdgcn_mfma_f32_16x16x32_f16(ahf[m], bhf[n], acc[m][n], 0, 0, 0);
#pragma unroll
        for (int m = 0; m < 4; ++m)
#pragma unroll
            for (int n = 0; n < 4; ++n)
                acc[m][n] = __builtin_amdgcn_mfma_f32_16x16x32_f16(ahf[m], blf[n], acc[m][n], 0, 0, 0);
#pragma unroll
        for (int m = 0; m < 4; ++m)
#pragma unroll
            for (int n = 0; n < 4; ++n)
                acc[m][n] = __builtin_amdgcn_mfma_f32_16x16x32_f16(alf[m], bhf[n], acc[m][n], 0, 0, 0);
        __builtin_amdgcn_s_setprio(0);
    };

    // ---- prologue: A(0),A(1) f32 prefetch; stage B(0); publish A(0) ----
    float4 rA0x = *(const float4*)(aptr);
    float4 rA0y = *(const float4*)(aptr + 4);
    stageB(0);
    float4 rA1x = *(const float4*)(aptr + BK);
    float4 rA1y = *(const float4*)(aptr + BK + 4);
    writeA(rA0x, rA0y, 0);                       // waits only on rA0 loads
    asm volatile("s_waitcnt lgkmcnt(0)" ::: "memory");
    asm volatile("s_barrier" ::: "memory");

    // ---- main loop, unrolled x2; one lgkm-drain + one plain barrier per step
    for (int t = 0; t < NT; t += 2) {
        {   // EVEN step t (p=0): consume A(t)/B(t); prep A(t+1)->buf1, B(t+1)
            asm volatile("s_waitcnt vmcnt(0)" ::: "memory");  // B(t), rA(t+1) landed
            if (t + 2 < NT) {
                rA0x = *(const float4*)(aptr + (t + 2) * BK);
                rA0y = *(const float4*)(aptr + (t + 2) * BK + 4);
            }
            readB();
            writeA(rA1x, rA1y, 1);                            // A(t+1) -> buf1
            asm volatile("s_waitcnt lgkmcnt(0)" ::: "memory");// B reads + A writes done
            stageB(t + 1);                                    // flies under MFMAs
            asm volatile("s_barrier" ::: "memory");           // A(t+1) published
            mfmaBlock(0);
        }
        {   // ODD step t+1 (p=1)
            const int tt = t + 1;
            asm volatile("s_waitcnt vmcnt(0)" ::: "memory");
            if (tt + 2 < NT) {
                rA1x = *(const float4*)(aptr + (tt + 2) * BK);
                rA1y = *(const float4*)(aptr + (tt + 2) * BK + 4);
            }
            readB();
            if (tt + 1 < NT) {
                writeA(rA0x, rA0y, 0);                        // A(t+2) -> buf0
                asm volatile("s_waitcnt lgkmcnt(0)" ::: "memory");
                stageB(tt + 1);
            } else {
                asm volatile("s_waitcnt lgkmcnt(0)" ::: "memory");
            }
            asm volatile("s_barrier" ::: "memory");
            mfmaBlock(1);
        }
    }
    __syncthreads();   // full drain before overlaying smem

    // ---- epilogue (overlay scratch on smem) ----
    float* rowssq = (float*)smem;                 // 256 B
    float* wvalp  = (float*)(smem + 256);         // 1 KiB
    int*   wcolp  = (int*)(smem + 1280);          // 1 KiB

    ssq += __shfl_xor(ssq, 1);
    ssq += __shfl_xor(ssq, 2);
    if (achk == 0) rowssq[arow] = ssq;

    // per-row argmax. acc[m][n][j] = S[16m + 4g + j][64wv + 16n + l15]
#pragma unroll
    for (int m = 0; m < 4; ++m) {
#pragma unroll
        for (int j = 0; j < 4; ++j) {
            float best = acc[m][0][j];
            int   bc   = wv * 64 + l15;
#pragma unroll
            for (int n = 1; n < 4; ++n) {
                float v = acc[m][n][j];
                int   c = wv * 64 + 16 * n + l15;
                if (v > best) { best = v; bc = c; }
            }
#pragma unroll
            for (int off = 1; off < 16; off <<= 1) {
                float ov = __shfl_xor(best, off);
                int   oc = __shfl_xor(bc, off);
                if (ov > best || (ov == best && oc < bc)) { best = ov; bc = oc; }
            }
            if (l15 == 0) {
                wvalp[wv * BM + 16 * m + 4 * g + j] = best;
                wcolp[wv * BM + 16 * m + 4 * g + j] = bc;
            }
        }
    }
    __syncthreads();

    if (tid < BM) {
        int r = tid;
        float best = wvalp[r]; int bc = wcolp[r];
#pragma unroll
        for (int w = 1; w < 4; ++w) {
            float ov = wvalp[w * BM + r]; int oc = wcolp[w * BM + r];
            if (ov > best || (ov == best && oc < bc)) { best = ov; bc = oc; }
        }
        float inv = 1.f / fmaxf(sqrtf(rowssq[r]), EPS);
        out[row0 + r]        = (float)bc;
        out[NTOT + row0 + r] = (float)PA[bc];
        float lsum = -(best * inv) * W[row0 + r];
#pragma unroll
        for (int off = 32; off >= 1; off >>= 1) lsum += __shfl_xor(lsum, off);
        if (tid == 0) partial[blockIdx.x] = lsum;
    }
}

// ---------------------------------------------------------------------------
// Deterministic final loss reduction: 4096 partials -> mean
// ---------------------------------------------------------------------------
__global__ void loss_reduce(const float* __restrict__ partial, float* __restrict__ out_loss) {
    __shared__ float s[256];
    float v = 0.f;
    for (int i = threadIdx.x; i < GRID_MAIN; i += 256) v += partial[i];
    s[threadIdx.x] = v;
    __syncthreads();
    for (int off = 128; off >= 1; off >>= 1) {
        if ((int)threadIdx.x < off) s[threadIdx.x] += s[threadIdx.x + off];
        __syncthreads();
    }
    if (threadIdx.x == 0) out_loss[0] = s[0] * (1.0f / (float)NTOT);
}

extern "C" void kernel_launch(void* const* d_in, const int* in_sizes, int n_in,
                              void* d_out, int out_size, void* d_ws, size_t ws_size,
                              hipStream_t stream) {
    const float* features = (const float*)d_in[0];
    const float* weight   = (const float*)d_in[1];
    const float* cc       = (const float*)d_in[2];
    const int*   pa       = (const int*)d_in[3];
    float* out = (float*)d_out;

    _Float16* bh = (_Float16*)d_ws;               // 192 KiB (stage-order)
    _Float16* bl = bh + KCL * DIM;                // 192 KiB
    float* partial = (float*)(bl + KCL * DIM);    // 16 KiB

    hipLaunchKernelGGL(prep_clusters, dim3(KCL), dim3(64), 0, stream, cc, bh, bl);
    hipLaunchKernelGGL(kmeans_main, dim3(GRID_MAIN), dim3(TBS), 0, stream,
                       features, weight, bh, bl, pa, out, partial);
    hipLaunchKernelGGL(loss_reduce, dim3(1), dim3(256), 0, stream, partial, out + 2 * NTOT);
}